// Round 1
// baseline (211.639 us; speedup 1.0000x reference)
//
#include <hip/hip_runtime.h>

// KnotAttention MI355X — round 8: single-gather fusion.
//
// R7 counters: knot_out 52.6us with MfmaUtil 12%, VALUBusy 15%, HBM 15% —
// pure gather-latency bound, and we pay the identical random 5-slot gather
// TWICE (logits pass + out pass). Fix: softmax normalizers are only 20
// scalars S[h][r], so pass 1 computes Q,K AND V from ONE staged tile and
// writes unnormalized Y = e*V (f16, [h][r][n][32], 128 MB, sequential).
// Pass 2 is a pure streaming normalize+reduce: 20 fully-coalesced read
// streams (1KB/instr/wave), no gather/MFMA/LDS — HBM-bound ~28us, likely
// faster since Y is still L3-resident. Old two-pass path kept as fallback
// if ws_size < 162 MB.

#define N_NODES 100000
#define D 128
#define H 4
#define R 5
#define NPB 32
#define THREADS 256
#define NBLOCKS (N_NODES / NPB)   // 3125

typedef _Float16 half_t;
typedef __attribute__((ext_vector_type(2))) _Float16 f16x2;
typedef __attribute__((ext_vector_type(4))) _Float16 f16x4;
typedef __attribute__((ext_vector_type(8))) _Float16 f16x8;
typedef __attribute__((ext_vector_type(4))) float f32x4;

typedef const __attribute__((address_space(1))) unsigned int* gp_t;
typedef __attribute__((address_space(3))) unsigned int* lp_t;

__device__ __forceinline__ void async_copy16(const void* g, void* l) {
    __builtin_amdgcn_global_load_lds((gp_t)g, (lp_t)l, 16, 0, 0);
}

// ------------- prep: weights -> A-frags, x -> f16, zero sums_p --------------
__global__ void prep(const float* __restrict__ x,
                     const float* __restrict__ wq, const float* __restrict__ wk,
                     const float* __restrict__ wv,
                     half_t* __restrict__ xh, half_t* __restrict__ wph,
                     float* __restrict__ sums_p)
{
    const int bid = blockIdx.x;
    const int t = threadIdx.x;
    if (bid < 44) {
        const float* src = (bid < 4) ? (wq + bid * 4096)
                         : (bid < 24) ? (wk + (bid - 4) * 4096)
                                      : (wv + (bid - 24) * 4096);
#pragma unroll
        for (int i = 0; i < 16; ++i) {
            int p = t * 16 + i;
            int j = p & 7, ln = (p >> 3) & 63, f = p >> 9;
            int kt = f & 3, mt = f >> 2;
            int d = kt * 32 + (ln >> 4) * 8 + j;
            int ko = mt * 16 + (ln & 15);
            wph[bid * 4096 + p] = (half_t)src[d * 32 + ko];
        }
    } else {
        if (bid == 44) {
            for (int i = t; i < 1280; i += THREADS) sums_p[i] = 0.f;
        }
        const int total = N_NODES * D / 8;
        const int nb = gridDim.x - 44;
        for (int i = (bid - 44) * THREADS + t; i < total; i += nb * THREADS) {
            const float4* s = (const float4*)x + (size_t)i * 2;
            float4 a = s[0], b = s[1];
            f16x8 h8 = {(half_t)a.x, (half_t)a.y, (half_t)a.z, (half_t)a.w,
                        (half_t)b.x, (half_t)b.y, (half_t)b.z, (half_t)b.w};
            *((f16x8*)xh + i) = h8;
        }
    }
}

// ---------- one burst: stage all 5 slot-tiles (10 DMA instrs/wave) ----------
// tile layout: slot r at r*8192; row stride 256 B; 16-B quad kq of row stored
// at kq^(row&7) (swizzle folded into the GLOBAL address; LDS dest is
// wave-uniform base + lane*16 as HW requires).
__device__ __forceinline__ void stage_all(const half_t* __restrict__ xh,
                                          const int* __restrict__ nbr,
                                          int base, char* tile, int tid)
{
    const int w = tid >> 6;
    const int lane = tid & 63;
    const int rr = lane >> 4, c = lane & 15;
    const int rowA = w * 4 + rr;          // 0..15
    const int rowB = rowA + 16;           // 16..31  (rowB&7 == rowA&7)
    const int nodeA = base + rowA;
    const int nodeB = base + rowB;
    int4 a4 = ((const int4*)nbr)[nodeA];
    int4 b4 = ((const int4*)nbr)[nodeB];
    int srcA[5] = {nodeA, a4.x, a4.y, a4.z, a4.w};
    int srcB[5] = {nodeB, b4.x, b4.y, b4.z, b4.w};
    const int sw = ((c ^ (rowA & 7)) << 4);
#pragma unroll
    for (int s = 0; s < 5; ++s) {
        const char* gA = (const char*)xh + (size_t)srcA[s] * 256 + sw;
        const char* gB = (const char*)xh + (size_t)srcB[s] * 256 + sw;
        async_copy16(gA, tile + s * 8192 + (w * 4) * 256);
        async_copy16(gB, tile + s * 8192 + (w * 4 + 16) * 256);
    }
}

// --------------------- A-frag preload: 8 loads ------------------------------
__device__ __forceinline__ void load_af(int mid, const half_t* __restrict__ wph,
                                        int lane, f16x8 (&af)[8])
{
#pragma unroll
    for (int kt = 0; kt < 4; ++kt) {
        af[kt * 2]     = *(const f16x8*)(wph + ((mid * 8 + kt) * 64 + lane) * 8);
        af[kt * 2 + 1] = *(const f16x8*)(wph + ((mid * 8 + 4 + kt) * 64 + lane) * 8);
    }
}

// -------- 32(kout) x 32(node) x 128(d) projection from LDS slot tile --------
__device__ __forceinline__ void proj32(const f16x8 (&af)[8], const half_t* tile,
                                       int lane, f32x4 (&acc)[2][2])
{
    const int l15 = lane & 15, q = lane >> 4;
#pragma unroll
    for (int mt = 0; mt < 2; ++mt)
#pragma unroll
        for (int nt = 0; nt < 2; ++nt)
            acc[mt][nt] = (f32x4){0.f, 0.f, 0.f, 0.f};
#pragma unroll
    for (int kt = 0; kt < 4; ++kt) {
#pragma unroll
        for (int nt = 0; nt < 2; ++nt) {
            int row = nt * 16 + l15;
            int sq = (kt * 4 + q) ^ (row & 7);
            f16x8 b = *(const f16x8*)(tile + row * 128 + sq * 8);
            acc[0][nt] = __builtin_amdgcn_mfma_f32_16x16x32_f16(af[kt * 2], b, acc[0][nt], 0, 0, 0);
            acc[1][nt] = __builtin_amdgcn_mfma_f32_16x16x32_f16(af[kt * 2 + 1], b, acc[1][nt], 0, 0, 0);
        }
    }
}

// ---------------- FUSED pass 1: Q,K -> e ; V -> Y = e*V ; sums --------------
// Y layout: f16 [h][r][n][32]  (node row = 64 B, sequential in n)
__global__ __launch_bounds__(THREADS, 4)
void knot_qkv(const half_t* __restrict__ xh, const int* __restrict__ nbr,
              const half_t* __restrict__ wph,
              half_t* __restrict__ Yg, float* __restrict__ sums_p)
{
    __shared__ __align__(16) char smem[5 * 8192];   // 40960 B exactly
    const int base = blockIdx.x * NPB;
    const int lane = threadIdx.x & 63;
    const int h = __builtin_amdgcn_readfirstlane((int)(threadIdx.x >> 6));
    const int l15 = lane & 15, q = lane >> 4;

    stage_all(xh, nbr, base, smem, threadIdx.x);

    f16x8 af[8];
    load_af(h, wph, lane, af);                       // Q-weights (mat h)
    __syncthreads();                                 // the ONLY pre-compute barrier

    f32x4 qf[2][2], kf[2][2];
    proj32(af, (const half_t*)smem, lane, qf);       // Q on slot-0 tile

    float esum[5];
#pragma unroll
    for (int r = 0; r < R; ++r) {
        // ---- K_r -> e ----
        load_af(4 + h * 5 + r, wph, lane, af);
        proj32(af, (const half_t*)(smem + r * 8192), lane, kf);

        float er[2];
        float es = 0.f;
#pragma unroll
        for (int nt = 0; nt < 2; ++nt) {
            float p = 0.f;
#pragma unroll
            for (int mt = 0; mt < 2; ++mt)
#pragma unroll
                for (int j = 0; j < 4; ++j)
                    p += qf[mt][nt][j] * kf[mt][nt][j];
            p += __shfl_xor(p, 16, 64);
            p += __shfl_xor(p, 32, 64);
            float e = __expf(p * 0.17677669529663688f);
            er[nt] = e;
            es += e;
        }
        es += __shfl_xor(es, 1, 64); es += __shfl_xor(es, 2, 64);
        es += __shfl_xor(es, 4, 64); es += __shfl_xor(es, 8, 64);
        esum[r] = es;    // summed over l15; q-copies identical (lane==0 atomics)

        // ---- V_r -> Y_r = e * V_r (unnormalized) ----
        load_af(24 + h * 5 + r, wph, lane, af);
        proj32(af, (const half_t*)(smem + r * 8192), lane, kf);   // kf reused as vf
        half_t* yr = Yg + ((size_t)(h * 5 + r) * N_NODES + base) * 32;
#pragma unroll
        for (int nt = 0; nt < 2; ++nt) {
            float w = er[nt];
#pragma unroll
            for (int mt = 0; mt < 2; ++mt) {
                f16x4 y4 = {(half_t)(kf[mt][nt][0] * w), (half_t)(kf[mt][nt][1] * w),
                            (half_t)(kf[mt][nt][2] * w), (half_t)(kf[mt][nt][3] * w)};
                *(f16x4*)(yr + (nt * 16 + l15) * 32 + mt * 16 + q * 4) = y4;
            }
        }
    }

#pragma unroll
    for (int r = 0; r < R; ++r)
        if (lane == 0)
            atomicAdd(&sums_p[(h * 5 + r) * 64 + (blockIdx.x & 63)], esum[r]);
}

// ------------- FUSED pass 2: pure streaming Z = sum_r Y_r / S_r -------------
// wave = head; lane -> (node = lane>>2, k = lane&3); per instr a wave reads a
// contiguous 1 KB (16 nodes x 64 B rows) of one [h][r] stream.
__global__ __launch_bounds__(256, 8)
void knot_stream(const half_t* __restrict__ Yg, const float* __restrict__ sums_p,
                 float* __restrict__ out)
{
    const int lane = threadIdx.x & 63;
    const int h = __builtin_amdgcn_readfirstlane((int)(threadIdx.x >> 6));
    const int n16 = lane >> 2, k = lane & 3;

    float inv[5];
#pragma unroll
    for (int r = 0; r < R; ++r) {
        float v = sums_p[(h * 5 + r) * 64 + lane];
        v += __shfl_xor(v, 1, 64);  v += __shfl_xor(v, 2, 64);
        v += __shfl_xor(v, 4, 64);  v += __shfl_xor(v, 8, 64);
        v += __shfl_xor(v, 16, 64); v += __shfl_xor(v, 32, 64);
        inv[r] = 1.0f / v;
    }

    const int base = blockIdx.x * 64;
#pragma unroll
    for (int i = 0; i < 4; ++i) {
        const int node = base + i * 16 + n16;
        if (node < N_NODES) {
            float z[8];
#pragma unroll
            for (int j = 0; j < 8; ++j) z[j] = 0.f;
#pragma unroll
            for (int r = 0; r < R; ++r) {
                f16x8 y = *(const f16x8*)(Yg + ((size_t)(h * 5 + r) * N_NODES + node) * 32 + k * 8);
#pragma unroll
                for (int j = 0; j < 8; ++j)
                    z[j] += inv[r] * (float)y[j];
            }
            float* dst = out + (size_t)node * D + h * 32 + k * 8;
            *(f32x4*)dst       = (f32x4){z[0], z[1], z[2], z[3]};
            *(f32x4*)(dst + 4) = (f32x4){z[4], z[5], z[6], z[7]};
        }
    }
}

// ------------------- fallback pass 1: Q,K -> e, sums ------------------------
__global__ __launch_bounds__(THREADS, 4)
void knot_logits(const half_t* __restrict__ xh, const int* __restrict__ nbr,
                 const half_t* __restrict__ wph,
                 half_t* __restrict__ eh, float* __restrict__ sums_p)
{
    __shared__ __align__(16) char smem[5 * 8192];
    const int base = blockIdx.x * NPB;
    const int lane = threadIdx.x & 63;
    const int h = __builtin_amdgcn_readfirstlane((int)(threadIdx.x >> 6));
    const int l15 = lane & 15, q = lane >> 4;

    stage_all(xh, nbr, base, smem, threadIdx.x);

    f16x8 af[8];
    load_af(h, wph, lane, af);
    __syncthreads();

    f32x4 qf[2][2], kf[2][2];
    proj32(af, (const half_t*)smem, lane, qf);

    f16x2 epk[5];
    float esum[5];
#pragma unroll
    for (int r = 0; r < R; ++r) {
        load_af(4 + h * 5 + r, wph, lane, af);
        proj32(af, (const half_t*)(smem + r * 8192), lane, kf);

        float es = 0.f;
#pragma unroll
        for (int nt = 0; nt < 2; ++nt) {
            float p = 0.f;
#pragma unroll
            for (int mt = 0; mt < 2; ++mt)
#pragma unroll
                for (int j = 0; j < 4; ++j)
                    p += qf[mt][nt][j] * kf[mt][nt][j];
            p += __shfl_xor(p, 16, 64);
            p += __shfl_xor(p, 32, 64);
            float e = __expf(p * 0.17677669529663688f);
            epk[r][nt] = (half_t)e;
            es += e;
        }
        es += __shfl_xor(es, 1, 64); es += __shfl_xor(es, 2, 64);
        es += __shfl_xor(es, 4, 64); es += __shfl_xor(es, 8, 64);
        esum[r] = es;
    }

#pragma unroll
    for (int r = 0; r < R; ++r) {
        if (q == 0) {
#pragma unroll
            for (int nt = 0; nt < 2; ++nt)
                eh[(size_t)(h * 5 + r) * N_NODES + base + nt * 16 + l15] = epk[r][nt];
        }
        if (lane == 0)
            atomicAdd(&sums_p[(h * 5 + r) * 64 + (blockIdx.x & 63)], esum[r]);
    }
}

// ------------------- fallback pass 2: V -> Z -> out -------------------------
#define ZS 132
__global__ __launch_bounds__(THREADS, 4)
void knot_out(const half_t* __restrict__ xh, const int* __restrict__ nbr,
              const half_t* __restrict__ wph, const half_t* __restrict__ eh,
              const float* __restrict__ sums_p, float* __restrict__ out)
{
    __shared__ __align__(16) char smem[5 * 8192];
    const int base = blockIdx.x * NPB;
    const int lane = threadIdx.x & 63;
    const int h = __builtin_amdgcn_readfirstlane((int)(threadIdx.x >> 6));
    const int l15 = lane & 15, q = lane >> 4;

    stage_all(xh, nbr, base, smem, threadIdx.x);

    float inv[5];
#pragma unroll
    for (int r = 0; r < R; ++r) {
        float v = sums_p[(h * 5 + r) * 64 + lane];
        v += __shfl_xor(v, 1, 64);  v += __shfl_xor(v, 2, 64);
        v += __shfl_xor(v, 4, 64);  v += __shfl_xor(v, 8, 64);
        v += __shfl_xor(v, 16, 64); v += __shfl_xor(v, 32, 64);
        inv[r] = 1.0f / v;
    }
    float ev[5][2];
#pragma unroll
    for (int r = 0; r < R; ++r)
#pragma unroll
        for (int nt = 0; nt < 2; ++nt)
            ev[r][nt] = (float)eh[(size_t)(h * 5 + r) * N_NODES + base + nt * 16 + l15];

    f16x8 af[8];
    load_af(24 + h * 5 + 0, wph, lane, af);
    __syncthreads();

    f32x4 z[2][2], vf[2][2];
#pragma unroll
    for (int mt = 0; mt < 2; ++mt)
#pragma unroll
        for (int nt = 0; nt < 2; ++nt)
            z[mt][nt] = (f32x4){0.f, 0.f, 0.f, 0.f};

#pragma unroll
    for (int r = 0; r < R; ++r) {
        proj32(af, (const half_t*)(smem + r * 8192), lane, vf);
        if (r < R - 1) load_af(24 + h * 5 + r + 1, wph, lane, af);
#pragma unroll
        for (int nt = 0; nt < 2; ++nt) {
            float w = ev[r][nt] * inv[r];
#pragma unroll
            for (int mt = 0; mt < 2; ++mt)
#pragma unroll
                for (int j = 0; j < 4; ++j)
                    z[mt][nt][j] += w * vf[mt][nt][j];
        }
    }

    __syncthreads();
    float* zt = (float*)smem;
#pragma unroll
    for (int mt = 0; mt < 2; ++mt)
#pragma unroll
        for (int nt = 0; nt < 2; ++nt) {
            int node = nt * 16 + l15;
            int col = h * 32 + mt * 16 + q * 4;
            *(f32x4*)(zt + node * ZS + col) = z[mt][nt];
        }
    __syncthreads();
    {
        const int row = threadIdx.x >> 3;
        const int c = threadIdx.x & 7;
        float* dst = out + (size_t)(base + row) * D + c * 16;
        const float* srcp = zt + row * ZS + c * 16;
#pragma unroll
        for (int i4 = 0; i4 < 4; ++i4)
            *(float4*)(dst + i4 * 4) = *(const float4*)(srcp + i4 * 4);
    }
}

// --------------------------------- launcher ---------------------------------
// ws (bytes): [0,5120) sums_p | [8192,+4e6) eh (fallback only)
//             [4194304,+360448) wph | [4718592,+25.6e6) xh
//             [33554432,+128e6) Y   -> fused path needs ws >= 161,554,432 B
extern "C" void kernel_launch(void* const* d_in, const int* in_sizes, int n_in,
                              void* d_out, int out_size, void* d_ws, size_t ws_size,
                              hipStream_t stream)
{
    const float* x   = (const float*)d_in[0];
    const int*   nbr = (const int*)d_in[1];
    const float* w_q = (const float*)d_in[2];
    const float* w_k = (const float*)d_in[3];
    const float* w_v = (const float*)d_in[4];
    float* out = (float*)d_out;

    float*  sums_p = (float*)d_ws;
    half_t* eh     = (half_t*)((char*)d_ws + 8192);
    half_t* wph    = (half_t*)((char*)d_ws + 4194304);
    half_t* xh     = (half_t*)((char*)d_ws + 4718592);
    half_t* Yg     = (half_t*)((char*)d_ws + 33554432ull);
    const size_t need = 33554432ull + 128000000ull;

    prep<<<44 + 2048, THREADS, 0, stream>>>(x, w_q, w_k, w_v, xh, wph, sums_p);
    if (ws_size >= need) {
        knot_qkv<<<NBLOCKS, THREADS, 0, stream>>>(xh, nbr, wph, Yg, sums_p);
        knot_stream<<<(N_NODES + 63) / 64, 256, 0, stream>>>(Yg, sums_p, out);
    } else {
        knot_logits<<<NBLOCKS, THREADS, 0, stream>>>(xh, nbr, wph, eh, sums_p);
        knot_out<<<NBLOCKS, THREADS, 0, stream>>>(xh, nbr, wph, eh, sums_p, out);
    }
}